// Round 6
// baseline (773.082 us; speedup 1.0000x reference)
//
#include <hip/hip_runtime.h>
#include <hip/hip_bf16.h>

#define N_NODES 50000
#define N_EDGES 800000
#define NNZ_H   800000
#define M_HE    10000
#define F_IN    128
#define F_HID   64

// bucket geometry for the two-level counting sort
#define SH_E 5
#define NB_E ((N_NODES + 31) >> 5)   // 1563
#define SH_H 3
#define NB_H ((M_HE + 7) >> 3)       // 1250
#define SH_N 5
#define NB_N ((N_NODES + 31) >> 5)   // 1563

// ---------------- pass A: bucket histograms ----------------
__global__ void k_hist(const int* __restrict__ e_col, const int* __restrict__ h_idx,
                       const int* __restrict__ n_idx,
                       int* __restrict__ bcntE, int* __restrict__ bcntH, int* __restrict__ bcntN) {
    int i = blockIdx.x * blockDim.x + threadIdx.x;
    if (i < N_EDGES) atomicAdd(&bcntE[e_col[i] >> SH_E], 1);
    if (i < NNZ_H) {
        atomicAdd(&bcntH[h_idx[i] >> SH_H], 1);
        atomicAdd(&bcntN[n_idx[i] >> SH_N], 1);
    }
}

// ---------------- block-wide exclusive scan helper (n <= ~2048) ----------------
__device__ void scan_block(const int* __restrict__ in, int* __restrict__ out, int n) {
    __shared__ int s[1024];
    int t = threadIdx.x;
    int chunk = (n + 1023) >> 10;
    int b = t * chunk;
    int e = min(b + chunk, n);
    int sum = 0;
    for (int i = b; i < e; ++i) sum += in[i];
    s[t] = sum;
    __syncthreads();
    for (int d = 1; d < 1024; d <<= 1) {
        int v = (t >= d) ? s[t - d] : 0;
        __syncthreads();
        s[t] += v;
        __syncthreads();
    }
    int run = (t > 0) ? s[t - 1] : 0;
    for (int i = b; i < e; ++i) { int v = in[i]; out[i] = run; run += v; }
}
__global__ void k_scan_buckets(const int* __restrict__ bcntE, int* __restrict__ boffE,
                               const int* __restrict__ bcntH, int* __restrict__ boffH,
                               const int* __restrict__ bcntN, int* __restrict__ boffN) {
    if (blockIdx.x == 0)      scan_block(bcntE, boffE, NB_E);
    else if (blockIdx.x == 1) scan_block(bcntH, boffH, NB_H);
    else                      scan_block(bcntN, boffN, NB_N);
}

// ---------------- pass B: scatter (key,payload) into bucket-contiguous regions ----------------
__global__ void k_bucket_scatter(const int* __restrict__ e_row, const int* __restrict__ e_col,
                                 const int* __restrict__ n_idx, const int* __restrict__ h_idx,
                                 const int* __restrict__ boffE, int* __restrict__ bcurE, int2* __restrict__ bkE,
                                 const int* __restrict__ boffH, int* __restrict__ bcurH, int2* __restrict__ bkH,
                                 const int* __restrict__ boffN, int* __restrict__ bcurN, int2* __restrict__ bkN) {
    int i = blockIdx.x * blockDim.x + threadIdx.x;
    if (i < N_EDGES) {
        int k = e_col[i];
        int b = k >> SH_E;
        int p = boffE[b] + atomicAdd(&bcurE[b], 1);
        bkE[p] = make_int2(k, e_row[i]);
    }
    if (i < NNZ_H) {
        int k = h_idx[i], v = n_idx[i];
        int b = k >> SH_H;
        int p = boffH[b] + atomicAdd(&bcurH[b], 1);
        bkH[p] = make_int2(k, v);
        b = v >> SH_N;
        p = boffN[b] + atomicAdd(&bcurN[b], 1);
        bkN[p] = make_int2(v, k);
    }
}

// ---------------- pass C: per-bucket CSR finalize (LDS rank, coalesced region writes) ----------------
__global__ void k_finalize(const int2* __restrict__ bkE, const int* __restrict__ boffE,
                           int* __restrict__ srtE, int* __restrict__ offE,
                           const int2* __restrict__ bkH, const int* __restrict__ boffH,
                           int* __restrict__ srtH, int* __restrict__ offH,
                           const int2* __restrict__ bkN, const int* __restrict__ boffN,
                           int* __restrict__ srtN, int* __restrict__ offN) {
    __shared__ int hist[32];
    __shared__ int koff[32];
    __shared__ int kcur[32];
    int b = blockIdx.x;
    const int2* bk; const int* boff; int* srt; int* off;
    int nb, sh, nkeys, total;
    if (b < NB_E) {
        bk = bkE; boff = boffE; srt = srtE; off = offE;
        nb = NB_E; sh = SH_E; nkeys = N_NODES; total = N_EDGES;
    } else if (b < NB_E + NB_H) {
        b -= NB_E;
        bk = bkH; boff = boffH; srt = srtH; off = offH;
        nb = NB_H; sh = SH_H; nkeys = M_HE; total = NNZ_H;
    } else {
        b -= NB_E + NB_H;
        bk = bkN; boff = boffN; srt = srtN; off = offN;
        nb = NB_N; sh = SH_N; nkeys = N_NODES; total = NNZ_H;
    }
    int kpb = 1 << sh;
    int k0 = b << sh;
    int beg = boff[b];
    int end = (b + 1 < nb) ? boff[b + 1] : total;
    if (threadIdx.x < kpb) hist[threadIdx.x] = 0;
    __syncthreads();
    for (int i = beg + threadIdx.x; i < end; i += 256)
        atomicAdd(&hist[bk[i].x - k0], 1);
    __syncthreads();
    if (threadIdx.x == 0) {
        int run = 0;
        for (int k = 0; k < kpb; ++k) { koff[k] = run; kcur[k] = 0; run += hist[k]; }
    }
    __syncthreads();
    if (threadIdx.x < kpb && (k0 + threadIdx.x) < nkeys)
        off[k0 + threadIdx.x] = beg + koff[threadIdx.x];
    if (b == nb - 1 && threadIdx.x == 0) off[nkeys] = total;
    for (int i = beg + threadIdx.x; i < end; i += 256) {
        int2 kv = bk[i];
        int lk = kv.x - k0;
        int pos = beg + koff[lk] + atomicAdd(&kcur[lk], 1);
        srt[pos] = kv.y;
    }
}

// ---------------- GEMM: (rows x K) @ (K x 64), w in LDS, 4 rows/block ----------------
// SCALE: multiply row result by dis[row] = rsqrt(deg+1), deg from CSR offsets
template<int K, bool SCALE>
__global__ void k_gemm(const float* __restrict__ xin, const float* __restrict__ w,
                       const int* __restrict__ offE, float* __restrict__ out) {
    __shared__ float wl[K * 64];
    __shared__ float xs[4][K];
    int tid = threadIdx.x;  // 256
    for (int i = tid; i < K * 64; i += 256) wl[i] = w[i];
    int r0 = blockIdx.x * 4;
    for (int i = tid; i < 4 * K; i += 256) {
        int rr = i / K, kk = i % K;
        xs[rr][kk] = xin[(size_t)(r0 + rr) * K + kk];
    }
    __syncthreads();
    int wv = tid >> 6, f = tid & 63;
    float acc = 0.0f;
#pragma unroll 8
    for (int k = 0; k < K; ++k)
        acc += xs[wv][k] * wl[k * 64 + f];
    if (SCALE) {
        int r = r0 + wv;
        float deg = (float)(offE[r + 1] - offE[r]);
        acc *= rsqrtf(deg + 1.0f);
    }
    out[(size_t)(r0 + wv) * 64 + f] = acc;
}

// ---------------- GCN gather on pre-scaled A': out = di*(sum + A'[i]) + b ----------------
template<bool ELU>
__global__ void k_gcn_gather(const int* __restrict__ off, const int* __restrict__ srcs,
                             const float* __restrict__ xw, const float* __restrict__ b,
                             float* __restrict__ out) {
    int wid = (blockIdx.x * blockDim.x + threadIdx.x) >> 6;
    int f = threadIdx.x & 63;
    if (wid >= N_NODES) return;
    int beg = off[wid], end = off[wid + 1];
    float a0 = 0, a1 = 0, a2 = 0, a3 = 0;
    int e = beg;
    for (; e + 4 <= end; e += 4) {
        int s0 = srcs[e], s1 = srcs[e + 1], s2 = srcs[e + 2], s3 = srcs[e + 3];
        a0 += xw[(size_t)s0 * 64 + f];
        a1 += xw[(size_t)s1 * 64 + f];
        a2 += xw[(size_t)s2 * 64 + f];
        a3 += xw[(size_t)s3 * 64 + f];
    }
    for (; e < end; ++e) a0 += xw[(size_t)srcs[e] * 64 + f];
    float acc = (a0 + a1) + (a2 + a3);
    float di = rsqrtf((float)(end - beg) + 1.0f);
    float v = di * (acc + xw[(size_t)wid * 64 + f]) + b[f];
    if (ELU) v = (v > 0.0f) ? v : expm1f(v);
    out[(size_t)wid * 64 + f] = v;
}

// ---------------- hyperedge gather: one BLOCK per hyperedge, 4-wave split + unroll ----------------
__global__ void k_he_gather(const int* __restrict__ off, const int* __restrict__ nodes,
                            const float* __restrict__ xw, float* __restrict__ C) {
    __shared__ float red[4][64];
    int he = blockIdx.x;
    int wv = threadIdx.x >> 6, f = threadIdx.x & 63;
    int beg = off[he], end = off[he + 1];
    int cnt = end - beg;
    int per = (cnt + 3) >> 2;
    int b0 = beg + wv * per;
    int e0 = min(b0 + per, end);
    float a0 = 0, a1 = 0, a2 = 0, a3 = 0;
    int e = b0;
    for (; e + 4 <= e0; e += 4) {
        int s0 = nodes[e], s1 = nodes[e + 1], s2 = nodes[e + 2], s3 = nodes[e + 3];
        a0 += xw[(size_t)s0 * 64 + f];
        a1 += xw[(size_t)s1 * 64 + f];
        a2 += xw[(size_t)s2 * 64 + f];
        a3 += xw[(size_t)s3 * 64 + f];
    }
    for (; e < e0; ++e) a0 += xw[(size_t)nodes[e] * 64 + f];
    red[wv][f] = (a0 + a1) + (a2 + a3);
    __syncthreads();
    if (wv == 0) {
        float tot = (red[0][f] + red[1][f]) + (red[2][f] + red[3][f]);
        float binv = (cnt > 0) ? 1.0f / (float)cnt : 0.0f;
        C[(size_t)he * 64 + f] = binv * tot;
    }
}

// ---------------- node gather from hyperedge feats: fused Dinv+bias+ELU ----------------
template<bool ELU>
__global__ void k_node_gather(const int* __restrict__ off, const int* __restrict__ hes,
                              const float* __restrict__ C, const float* __restrict__ b,
                              float* __restrict__ out) {
    int wid = (blockIdx.x * blockDim.x + threadIdx.x) >> 6;
    int f = threadIdx.x & 63;
    if (wid >= N_NODES) return;
    int beg = off[wid], end = off[wid + 1];
    float a0 = 0, a1 = 0, a2 = 0, a3 = 0;
    int e = beg;
    for (; e + 4 <= end; e += 4) {
        int s0 = hes[e], s1 = hes[e + 1], s2 = hes[e + 2], s3 = hes[e + 3];
        a0 += C[(size_t)s0 * 64 + f];
        a1 += C[(size_t)s1 * 64 + f];
        a2 += C[(size_t)s2 * 64 + f];
        a3 += C[(size_t)s3 * 64 + f];
    }
    for (; e < end; ++e) a0 += C[(size_t)hes[e] * 64 + f];
    float acc = (a0 + a1) + (a2 + a3);
    float dinv = (end > beg) ? 1.0f / (float)(end - beg) : 0.0f;
    float v = dinv * acc + b[f];
    if (ELU) v = (v > 0.0f) ? v : expm1f(v);
    out[(size_t)wid * 64 + f] = v;
}

// ---------------- fusion (float4) ----------------
__global__ void k_fuse(const float4* __restrict__ xs, const float4* __restrict__ xd,
                       const float* __restrict__ gate, float4* __restrict__ z) {
    int t = blockIdx.x * blockDim.x + threadIdx.x;
    if (t >= N_NODES * 16) return;
    float a = 1.0f / (1.0f + expf(-gate[0]));
    float4 s = xs[t], d = xd[t];
    float4 o;
    o.x = a * s.x + (1.0f - a) * d.x;
    o.y = a * s.y + (1.0f - a) * d.y;
    o.z = a * s.z + (1.0f - a) * d.z;
    o.w = a * s.w + (1.0f - a) * d.w;
    z[t] = o;
}

extern "C" void kernel_launch(void* const* d_in, const int* in_sizes, int n_in,
                              void* d_out, int out_size, void* d_ws, size_t ws_size,
                              hipStream_t stream) {
    const float* x      = (const float*)d_in[0];
    const int*   ei     = (const int*)d_in[1];
    const int*   hei    = (const int*)d_in[2];
    const float* gcn1_w = (const float*)d_in[3];
    const float* gcn1_b = (const float*)d_in[4];
    const float* gcn2_w = (const float*)d_in[5];
    const float* gcn2_b = (const float*)d_in[6];
    const float* hyp1_w = (const float*)d_in[7];
    const float* hyp1_b = (const float*)d_in[8];
    const float* hyp2_w = (const float*)d_in[9];
    const float* hyp2_b = (const float*)d_in[10];
    const float* gate   = (const float*)d_in[11];
    float* out = (float*)d_out;

    const int* e_row = ei;               // sources
    const int* e_col = ei + N_EDGES;     // targets
    const int* n_idx = hei;              // node ids
    const int* h_idx = hei + NNZ_H;      // hyperedge ids

    const size_t NV = (size_t)N_NODES * 64;
    float* z_out  = out;
    float* xs_out = out + NV;
    float* xd_out = out + 2 * NV;

    // ---- workspace layout ----
    float* A    = (float*)d_ws;          // N*64 floats
    float* AGG  = A + NV;                // N*64
    float* C    = AGG + NV;              // M*64
    int* srtE = (int*)(C + (size_t)M_HE * 64);  // E
    int* srtH = srtE + N_EDGES;          // NNZ
    int* srtN = srtH + NNZ_H;            // NNZ
    int* offE = srtN + NNZ_H;            // N+1
    int* offH = offE + (N_NODES + 1);    // M+1
    int* offN = offH + (M_HE + 1);       // N+1
    // contiguous zero block: bucket counts + cursors
    int* bcntE = offN + (N_NODES + 1);   // NB_E
    int* bcntH = bcntE + NB_E;           // NB_H
    int* bcntN = bcntH + NB_H;           // NB_N
    int* bcurE = bcntN + NB_N;           // NB_E
    int* bcurH = bcurE + NB_E;           // NB_H
    int* bcurN = bcurH + NB_H;           // NB_N
    // scan outputs (no zeroing needed)
    int* boffE = bcurN + NB_N;           // NB_E
    int* boffH = boffE + NB_E;           // NB_H
    int* boffN = boffH + NB_H;           // NB_N
    const size_t zero_ints = 2 * (size_t)(NB_E + NB_H + NB_N);
    // bucket staging aliases A/AGG (free during CSR build)
    int2* bkE = (int2*)A;                     // 800K int2 (6.4 MB of A's 12.8)
    int2* bkH = (int2*)(A + 2 * (size_t)N_EDGES);  // next 6.4 MB of A
    int2* bkN = (int2*)AGG;                   // 6.4 MB of AGG

    const int BLK = 256;
    const int gBig = (N_EDGES + BLK - 1) / BLK;       // covers E == NNZ
    const int gWN  = N_NODES / 4;                      // 12500 (4 rows/block)
    const int gF4  = (N_NODES * 16 + BLK - 1) / BLK;

    // ---- CSR build: two-level bucketed counting sort ----
    hipMemsetAsync(bcntE, 0, zero_ints * sizeof(int), stream);
    k_hist<<<gBig, BLK, 0, stream>>>(e_col, h_idx, n_idx, bcntE, bcntH, bcntN);
    k_scan_buckets<<<3, 1024, 0, stream>>>(bcntE, boffE, bcntH, boffH, bcntN, boffN);
    k_bucket_scatter<<<gBig, BLK, 0, stream>>>(e_row, e_col, n_idx, h_idx,
                                               boffE, bcurE, bkE,
                                               boffH, bcurH, bkH,
                                               boffN, bcurN, bkN);
    k_finalize<<<NB_E + NB_H + NB_N, BLK, 0, stream>>>(bkE, boffE, srtE, offE,
                                                       bkH, boffH, srtH, offH,
                                                       bkN, boffN, srtN, offN);

    // ---- GCN layer 1: A = dis.*(x@w1) ; AGG = ELU(di*(gather+self) + b1) ----
    k_gemm<F_IN, true><<<gWN, BLK, 0, stream>>>(x, gcn1_w, offE, A);
    k_gcn_gather<true><<<gWN, BLK, 0, stream>>>(offE, srtE, A, gcn1_b, AGG);

    // ---- GCN layer 2 ----
    k_gemm<F_HID, true><<<gWN, BLK, 0, stream>>>(AGG, gcn2_w, offE, A);
    k_gcn_gather<false><<<gWN, BLK, 0, stream>>>(offE, srtE, A, gcn2_b, xs_out);

    // ---- Hyper layer 1 ----
    k_gemm<F_IN, false><<<gWN, BLK, 0, stream>>>(x, hyp1_w, nullptr, A);
    k_he_gather<<<M_HE, BLK, 0, stream>>>(offH, srtH, A, C);
    k_node_gather<true><<<gWN, BLK, 0, stream>>>(offN, srtN, C, hyp1_b, AGG);

    // ---- Hyper layer 2 ----
    k_gemm<F_HID, false><<<gWN, BLK, 0, stream>>>(AGG, hyp2_w, nullptr, A);
    k_he_gather<<<M_HE, BLK, 0, stream>>>(offH, srtH, A, C);
    k_node_gather<false><<<gWN, BLK, 0, stream>>>(offN, srtN, C, hyp2_b, xd_out);

    // ---- fusion ----
    k_fuse<<<gF4, BLK, 0, stream>>>((const float4*)xs_out, (const float4*)xd_out, gate, (float4*)z_out);

    (void)in_sizes; (void)n_in; (void)out_size; (void)ws_size;
}

// Round 7
// 455.479 us; speedup vs baseline: 1.6973x; 1.6973x over previous
//
#include <hip/hip_runtime.h>
#include <hip/hip_bf16.h>

#define N_NODES 50000
#define N_EDGES 800000
#define NNZ_H   800000
#define M_HE    10000
#define F_IN    128
#define F_HID   64

// coarse-bucket geometry for the two-level counting sort
#define SH_E 10
#define NB_E ((N_NODES + 1023) >> 10)   // 49
#define SH_H 7
#define NB_H ((M_HE + 127) >> 7)        // 79
#define SH_N 10
#define NB_N ((N_NODES + 1023) >> 10)   // 49
#define TILE 4096
#define GB   ((N_EDGES + TILE - 1) / TILE)   // 196 (E == NNZ)

// ---------------- pass A: fused bucket histograms (LDS pre-aggregated) ----------------
__global__ void k_hist_all(const int* __restrict__ e_col, const int* __restrict__ h_idx,
                           const int* __restrict__ n_idx,
                           int* __restrict__ bcntE, int* __restrict__ bcntH, int* __restrict__ bcntN) {
    __shared__ int hE[NB_E], hH[NB_H], hN[NB_N];
    for (int i = threadIdx.x; i < NB_E; i += 256) hE[i] = 0;
    for (int i = threadIdx.x; i < NB_H; i += 256) hH[i] = 0;
    for (int i = threadIdx.x; i < NB_N; i += 256) hN[i] = 0;
    __syncthreads();
    int stride = gridDim.x * 256;
    for (int i = blockIdx.x * 256 + threadIdx.x; i < N_EDGES; i += stride) {
        atomicAdd(&hE[e_col[i] >> SH_E], 1);
        atomicAdd(&hH[h_idx[i] >> SH_H], 1);
        atomicAdd(&hN[n_idx[i] >> SH_N], 1);
    }
    __syncthreads();
    for (int i = threadIdx.x; i < NB_E; i += 256) if (hE[i]) atomicAdd(&bcntE[i], hE[i]);
    for (int i = threadIdx.x; i < NB_H; i += 256) if (hH[i]) atomicAdd(&bcntH[i], hH[i]);
    for (int i = threadIdx.x; i < NB_N; i += 256) if (hN[i]) atomicAdd(&bcntN[i], hN[i]);
}

// ---------------- block-wide exclusive scan helper (n <= 1024) ----------------
__device__ void scan_block(const int* __restrict__ in, int* __restrict__ out, int n) {
    __shared__ int s[1024];
    int t = threadIdx.x;
    int chunk = (n + 1023) >> 10;
    int b = t * chunk;
    int e = min(b + chunk, n);
    int sum = 0;
    for (int i = b; i < e; ++i) sum += in[i];
    s[t] = sum;
    __syncthreads();
    for (int d = 1; d < 1024; d <<= 1) {
        int v = (t >= d) ? s[t - d] : 0;
        __syncthreads();
        s[t] += v;
        __syncthreads();
    }
    int run = (t > 0) ? s[t - 1] : 0;
    for (int i = b; i < e; ++i) { int v = in[i]; out[i] = run; run += v; }
}
__global__ void k_scan_buckets(const int* __restrict__ bcntE, int* __restrict__ boffE,
                               const int* __restrict__ bcntH, int* __restrict__ boffH,
                               const int* __restrict__ bcntN, int* __restrict__ boffN) {
    if (blockIdx.x == 0)      scan_block(bcntE, boffE, NB_E);
    else if (blockIdx.x == 1) scan_block(bcntH, boffH, NB_H);
    else                      scan_block(bcntN, boffN, NB_N);
}

// ---------------- pass B: chunked scatter with LDS staging (write-combining) ----------------
#define NBMAX 80
__device__ void chunk_scatter(const int* __restrict__ keys, const int* __restrict__ vals,
                              int n, int sh, int nb,
                              const int* __restrict__ boff, int* __restrict__ bcur,
                              int2* __restrict__ bk, int blk) {
    __shared__ int h[NBMAX], loc[NBMAX], base[NBMAX], hc[NBMAX];
    __shared__ int2 buf[TILE];
    int t0 = blk * TILE;
    int tend = min(t0 + TILE, n);
    int cnt = tend - t0;
    for (int b = threadIdx.x; b < nb; b += 256) { h[b] = 0; hc[b] = 0; }
    __syncthreads();
    for (int i = t0 + threadIdx.x; i < tend; i += 256)
        atomicAdd(&h[keys[i] >> sh], 1);
    __syncthreads();
    if (threadIdx.x == 0) {
        int run = 0;
        for (int b = 0; b < nb; ++b) { loc[b] = run; run += h[b]; }
    }
    __syncthreads();
    if (threadIdx.x < nb)
        base[threadIdx.x] = boff[threadIdx.x] + atomicAdd(&bcur[threadIdx.x], h[threadIdx.x]);
    __syncthreads();
    for (int i = t0 + threadIdx.x; i < tend; i += 256) {
        int k = keys[i];
        int b = k >> sh;
        int r = loc[b] + atomicAdd(&hc[b], 1);
        buf[r] = make_int2(k, vals[i]);
    }
    __syncthreads();
    for (int j = threadIdx.x; j < cnt; j += 256) {
        int2 kv = buf[j];
        int b = kv.x >> sh;
        bk[base[b] + (j - loc[b])] = kv;   // contiguous per-bucket runs, block-owned
    }
}
__global__ void k_chunk_all(const int* __restrict__ e_row, const int* __restrict__ e_col,
                            const int* __restrict__ n_idx, const int* __restrict__ h_idx,
                            const int* __restrict__ boffE, int* __restrict__ bcurE, int2* __restrict__ bkE,
                            const int* __restrict__ boffH, int* __restrict__ bcurH, int2* __restrict__ bkH,
                            const int* __restrict__ boffN, int* __restrict__ bcurN, int2* __restrict__ bkN) {
    int gb = blockIdx.x;
    if (gb < GB)            chunk_scatter(e_col, e_row, N_EDGES, SH_E, NB_E, boffE, bcurE, bkE, gb);
    else if (gb < 2 * GB)   chunk_scatter(h_idx, n_idx, NNZ_H,  SH_H, NB_H, boffH, bcurH, bkH, gb - GB);
    else                    chunk_scatter(n_idx, h_idx, NNZ_H,  SH_N, NB_N, boffN, bcurN, bkN, gb - 2 * GB);
}

// ---------------- pass C: per-bucket CSR finalize (LDS key-hist + scan + rank) ----------------
__global__ void k_fin_all(const int2* __restrict__ bkE, const int* __restrict__ boffE,
                          int* __restrict__ srtE, int* __restrict__ offE,
                          const int2* __restrict__ bkH, const int* __restrict__ boffH,
                          int* __restrict__ srtH, int* __restrict__ offH,
                          const int2* __restrict__ bkN, const int* __restrict__ boffN,
                          int* __restrict__ srtN, int* __restrict__ offN) {
    __shared__ int koff[1024];
    __shared__ int kcur[1024];
    __shared__ int tsum[256];
    int b = blockIdx.x;
    const int2* bk; const int* boff; int* srt; int* off;
    int nb, sh, nkeys, total;
    if (b < NB_E) {
        bk = bkE; boff = boffE; srt = srtE; off = offE;
        nb = NB_E; sh = SH_E; nkeys = N_NODES; total = N_EDGES;
    } else if (b < NB_E + NB_H) {
        b -= NB_E;
        bk = bkH; boff = boffH; srt = srtH; off = offH;
        nb = NB_H; sh = SH_H; nkeys = M_HE; total = NNZ_H;
    } else {
        b -= NB_E + NB_H;
        bk = bkN; boff = boffN; srt = srtN; off = offN;
        nb = NB_N; sh = SH_N; nkeys = N_NODES; total = NNZ_H;
    }
    int kpb = 1 << sh;
    int k0 = b << sh;
    int beg = boff[b];
    int end = (b + 1 < nb) ? boff[b + 1] : total;
    for (int k = threadIdx.x; k < kpb; k += 256) { koff[k] = 0; kcur[k] = 0; }
    __syncthreads();
    for (int i = beg + threadIdx.x; i < end; i += 256)
        atomicAdd(&koff[bk[i].x - k0], 1);
    __syncthreads();
    // block exclusive scan of koff[0..kpb)
    int CH = (kpb + 255) >> 8;
    int t = threadIdx.x;
    int c0 = t * CH;
    int lsum = 0;
    for (int c = 0; c < CH; ++c) { int k = c0 + c; if (k < kpb) lsum += koff[k]; }
    tsum[t] = lsum;
    __syncthreads();
    for (int d = 1; d < 256; d <<= 1) {
        int v = (t >= d) ? tsum[t - d] : 0;
        __syncthreads();
        tsum[t] += v;
        __syncthreads();
    }
    int run = (t > 0) ? tsum[t - 1] : 0;
    for (int c = 0; c < CH; ++c) {
        int k = c0 + c;
        if (k < kpb) { int v = koff[k]; koff[k] = run; run += v; }
    }
    __syncthreads();
    // CSR offsets
    for (int k = threadIdx.x; k < kpb; k += 256)
        if (k0 + k < nkeys) off[k0 + k] = beg + koff[k];
    if (b == nb - 1 && threadIdx.x == 0) off[nkeys] = total;
    // rank + scatter payload (block-owned contiguous window)
    for (int i = beg + threadIdx.x; i < end; i += 256) {
        int2 kv = bk[i];
        int lk = kv.x - k0;
        int pos = beg + koff[lk] + atomicAdd(&kcur[lk], 1);
        srt[pos] = kv.y;
    }
}

// ---------------- GEMM: (rows x K) @ (K x 64), w in LDS, 4 rows/block ----------------
template<int K, bool SCALE>
__global__ void k_gemm(const float* __restrict__ xin, const float* __restrict__ w,
                       const int* __restrict__ offE, float* __restrict__ out) {
    __shared__ float wl[K * 64];
    __shared__ float xs[4][K];
    int tid = threadIdx.x;  // 256
    for (int i = tid; i < K * 64; i += 256) wl[i] = w[i];
    int r0 = blockIdx.x * 4;
    for (int i = tid; i < 4 * K; i += 256) {
        int rr = i / K, kk = i % K;
        xs[rr][kk] = xin[(size_t)(r0 + rr) * K + kk];
    }
    __syncthreads();
    int wv = tid >> 6, f = tid & 63;
    float acc = 0.0f;
#pragma unroll 8
    for (int k = 0; k < K; ++k)
        acc += xs[wv][k] * wl[k * 64 + f];
    if (SCALE) {
        int r = r0 + wv;
        float deg = (float)(offE[r + 1] - offE[r]);
        acc *= rsqrtf(deg + 1.0f);
    }
    out[(size_t)(r0 + wv) * 64 + f] = acc;
}

// ---------------- GCN gather on pre-scaled A': out = di*(sum + A'[i]) + b ----------------
template<bool ELU>
__global__ void k_gcn_gather(const int* __restrict__ off, const int* __restrict__ srcs,
                             const float* __restrict__ xw, const float* __restrict__ b,
                             float* __restrict__ out) {
    int wid = (blockIdx.x * blockDim.x + threadIdx.x) >> 6;
    int f = threadIdx.x & 63;
    if (wid >= N_NODES) return;
    int beg = off[wid], end = off[wid + 1];
    float a0 = 0, a1 = 0, a2 = 0, a3 = 0;
    int e = beg;
    for (; e + 4 <= end; e += 4) {
        int s0 = srcs[e], s1 = srcs[e + 1], s2 = srcs[e + 2], s3 = srcs[e + 3];
        a0 += xw[(size_t)s0 * 64 + f];
        a1 += xw[(size_t)s1 * 64 + f];
        a2 += xw[(size_t)s2 * 64 + f];
        a3 += xw[(size_t)s3 * 64 + f];
    }
    for (; e < end; ++e) a0 += xw[(size_t)srcs[e] * 64 + f];
    float acc = (a0 + a1) + (a2 + a3);
    float di = rsqrtf((float)(end - beg) + 1.0f);
    float v = di * (acc + xw[(size_t)wid * 64 + f]) + b[f];
    if (ELU) v = (v > 0.0f) ? v : expm1f(v);
    out[(size_t)wid * 64 + f] = v;
}

// ---------------- hyperedge gather: one BLOCK per hyperedge, 4-wave split + unroll ----------------
__global__ void k_he_gather(const int* __restrict__ off, const int* __restrict__ nodes,
                            const float* __restrict__ xw, float* __restrict__ C) {
    __shared__ float red[4][64];
    int he = blockIdx.x;
    int wv = threadIdx.x >> 6, f = threadIdx.x & 63;
    int beg = off[he], end = off[he + 1];
    int cnt = end - beg;
    int per = (cnt + 3) >> 2;
    int b0 = beg + wv * per;
    int e0 = min(b0 + per, end);
    float a0 = 0, a1 = 0, a2 = 0, a3 = 0;
    int e = b0;
    for (; e + 4 <= e0; e += 4) {
        int s0 = nodes[e], s1 = nodes[e + 1], s2 = nodes[e + 2], s3 = nodes[e + 3];
        a0 += xw[(size_t)s0 * 64 + f];
        a1 += xw[(size_t)s1 * 64 + f];
        a2 += xw[(size_t)s2 * 64 + f];
        a3 += xw[(size_t)s3 * 64 + f];
    }
    for (; e < e0; ++e) a0 += xw[(size_t)nodes[e] * 64 + f];
    red[wv][f] = (a0 + a1) + (a2 + a3);
    __syncthreads();
    if (wv == 0) {
        float tot = (red[0][f] + red[1][f]) + (red[2][f] + red[3][f]);
        float binv = (cnt > 0) ? 1.0f / (float)cnt : 0.0f;
        C[(size_t)he * 64 + f] = binv * tot;
    }
}

// ---------------- node gather from hyperedge feats: fused Dinv+bias+ELU ----------------
template<bool ELU>
__global__ void k_node_gather(const int* __restrict__ off, const int* __restrict__ hes,
                              const float* __restrict__ C, const float* __restrict__ b,
                              float* __restrict__ out) {
    int wid = (blockIdx.x * blockDim.x + threadIdx.x) >> 6;
    int f = threadIdx.x & 63;
    if (wid >= N_NODES) return;
    int beg = off[wid], end = off[wid + 1];
    float a0 = 0, a1 = 0, a2 = 0, a3 = 0;
    int e = beg;
    for (; e + 4 <= end; e += 4) {
        int s0 = hes[e], s1 = hes[e + 1], s2 = hes[e + 2], s3 = hes[e + 3];
        a0 += C[(size_t)s0 * 64 + f];
        a1 += C[(size_t)s1 * 64 + f];
        a2 += C[(size_t)s2 * 64 + f];
        a3 += C[(size_t)s3 * 64 + f];
    }
    for (; e < end; ++e) a0 += C[(size_t)hes[e] * 64 + f];
    float acc = (a0 + a1) + (a2 + a3);
    float dinv = (end > beg) ? 1.0f / (float)(end - beg) : 0.0f;
    float v = dinv * acc + b[f];
    if (ELU) v = (v > 0.0f) ? v : expm1f(v);
    out[(size_t)wid * 64 + f] = v;
}

// ---------------- fusion (float4) ----------------
__global__ void k_fuse(const float4* __restrict__ xs, const float4* __restrict__ xd,
                       const float* __restrict__ gate, float4* __restrict__ z) {
    int t = blockIdx.x * blockDim.x + threadIdx.x;
    if (t >= N_NODES * 16) return;
    float a = 1.0f / (1.0f + expf(-gate[0]));
    float4 s = xs[t], d = xd[t];
    float4 o;
    o.x = a * s.x + (1.0f - a) * d.x;
    o.y = a * s.y + (1.0f - a) * d.y;
    o.z = a * s.z + (1.0f - a) * d.z;
    o.w = a * s.w + (1.0f - a) * d.w;
    z[t] = o;
}

extern "C" void kernel_launch(void* const* d_in, const int* in_sizes, int n_in,
                              void* d_out, int out_size, void* d_ws, size_t ws_size,
                              hipStream_t stream) {
    const float* x      = (const float*)d_in[0];
    const int*   ei     = (const int*)d_in[1];
    const int*   hei    = (const int*)d_in[2];
    const float* gcn1_w = (const float*)d_in[3];
    const float* gcn1_b = (const float*)d_in[4];
    const float* gcn2_w = (const float*)d_in[5];
    const float* gcn2_b = (const float*)d_in[6];
    const float* hyp1_w = (const float*)d_in[7];
    const float* hyp1_b = (const float*)d_in[8];
    const float* hyp2_w = (const float*)d_in[9];
    const float* hyp2_b = (const float*)d_in[10];
    const float* gate   = (const float*)d_in[11];
    float* out = (float*)d_out;

    const int* e_row = ei;               // sources
    const int* e_col = ei + N_EDGES;     // targets
    const int* n_idx = hei;              // node ids
    const int* h_idx = hei + NNZ_H;      // hyperedge ids

    const size_t NV = (size_t)N_NODES * 64;
    float* z_out  = out;
    float* xs_out = out + NV;
    float* xd_out = out + 2 * NV;

    // ---- workspace layout ----
    float* A    = (float*)d_ws;          // N*64 floats
    float* AGG  = A + NV;                // N*64
    float* C    = AGG + NV;              // M*64
    int* srtE = (int*)(C + (size_t)M_HE * 64);  // E
    int* srtH = srtE + N_EDGES;          // NNZ
    int* srtN = srtH + NNZ_H;            // NNZ
    int* offE = srtN + NNZ_H;            // N+1
    int* offH = offE + (N_NODES + 1);    // M+1
    int* offN = offH + (M_HE + 1);       // N+1
    // contiguous zero block: bucket counts + cursors
    int* bcntE = offN + (N_NODES + 1);   // NB_E
    int* bcntH = bcntE + NB_E;           // NB_H
    int* bcntN = bcntH + NB_H;           // NB_N
    int* bcurE = bcntN + NB_N;           // NB_E
    int* bcurH = bcurE + NB_E;           // NB_H
    int* bcurN = bcurH + NB_H;           // NB_N
    // scan outputs (no zeroing needed)
    int* boffE = bcurN + NB_N;           // NB_E
    int* boffH = boffE + NB_E;           // NB_H
    int* boffN = boffH + NB_H;           // NB_N
    const size_t zero_ints = 2 * (size_t)(NB_E + NB_H + NB_N);
    // bucket staging aliases A/AGG (free during CSR build)
    int2* bkE = (int2*)A;                          // 6.4 MB
    int2* bkH = (int2*)(A + 2 * (size_t)N_EDGES);  // 6.4 MB
    int2* bkN = (int2*)AGG;                        // 6.4 MB

    const int BLK = 256;
    const int gWN  = N_NODES / 4;                      // 12500 (4 rows/block)
    const int gF4  = (N_NODES * 16 + BLK - 1) / BLK;

    // ---- CSR build: two-level bucketed counting sort with chunked (write-combined) scatter ----
    hipMemsetAsync(bcntE, 0, zero_ints * sizeof(int), stream);
    k_hist_all<<<256, BLK, 0, stream>>>(e_col, h_idx, n_idx, bcntE, bcntH, bcntN);
    k_scan_buckets<<<3, 1024, 0, stream>>>(bcntE, boffE, bcntH, boffH, bcntN, boffN);
    k_chunk_all<<<3 * GB, BLK, 0, stream>>>(e_row, e_col, n_idx, h_idx,
                                            boffE, bcurE, bkE,
                                            boffH, bcurH, bkH,
                                            boffN, bcurN, bkN);
    k_fin_all<<<NB_E + NB_H + NB_N, BLK, 0, stream>>>(bkE, boffE, srtE, offE,
                                                      bkH, boffH, srtH, offH,
                                                      bkN, boffN, srtN, offN);

    // ---- GCN layer 1: A = dis.*(x@w1) ; AGG = ELU(di*(gather+self) + b1) ----
    k_gemm<F_IN, true><<<gWN, BLK, 0, stream>>>(x, gcn1_w, offE, A);
    k_gcn_gather<true><<<gWN, BLK, 0, stream>>>(offE, srtE, A, gcn1_b, AGG);

    // ---- GCN layer 2 ----
    k_gemm<F_HID, true><<<gWN, BLK, 0, stream>>>(AGG, gcn2_w, offE, A);
    k_gcn_gather<false><<<gWN, BLK, 0, stream>>>(offE, srtE, A, gcn2_b, xs_out);

    // ---- Hyper layer 1 ----
    k_gemm<F_IN, false><<<gWN, BLK, 0, stream>>>(x, hyp1_w, nullptr, A);
    k_he_gather<<<M_HE, BLK, 0, stream>>>(offH, srtH, A, C);
    k_node_gather<true><<<gWN, BLK, 0, stream>>>(offN, srtN, C, hyp1_b, AGG);

    // ---- Hyper layer 2 ----
    k_gemm<F_HID, false><<<gWN, BLK, 0, stream>>>(AGG, hyp2_w, nullptr, A);
    k_he_gather<<<M_HE, BLK, 0, stream>>>(offH, srtH, A, C);
    k_node_gather<false><<<gWN, BLK, 0, stream>>>(offN, srtN, C, hyp2_b, xd_out);

    // ---- fusion ----
    k_fuse<<<gF4, BLK, 0, stream>>>((const float4*)xs_out, (const float4*)xd_out, gate, (float4*)z_out);

    (void)in_sizes; (void)n_in; (void)out_size; (void)ws_size;
}

// Round 8
// 365.906 us; speedup vs baseline: 2.1128x; 1.2448x over previous
//
#include <hip/hip_runtime.h>
#include <hip/hip_bf16.h>

#define N_NODES 50000
#define N_EDGES 800000
#define NNZ_H   800000
#define M_HE    10000
#define F_IN    128
#define F_HID   64

// coarse-bucket geometry for the two-level counting sort
#define SH_E 10
#define NB_E ((N_NODES + 1023) >> 10)   // 49
#define SH_H 7
#define NB_H ((M_HE + 127) >> 7)        // 79
#define SH_N 10
#define NB_N ((N_NODES + 1023) >> 10)   // 49
#define TILE 4096
#define GB   ((N_EDGES + TILE - 1) / TILE)   // 196 (E == NNZ)

// ---------------- pass A: fused bucket histograms (LDS pre-aggregated) ----------------
__global__ void k_hist_all(const int* __restrict__ e_col, const int* __restrict__ h_idx,
                           const int* __restrict__ n_idx,
                           int* __restrict__ bcntE, int* __restrict__ bcntH, int* __restrict__ bcntN) {
    __shared__ int hE[NB_E], hH[NB_H], hN[NB_N];
    for (int i = threadIdx.x; i < NB_E; i += 256) hE[i] = 0;
    for (int i = threadIdx.x; i < NB_H; i += 256) hH[i] = 0;
    for (int i = threadIdx.x; i < NB_N; i += 256) hN[i] = 0;
    __syncthreads();
    int stride = gridDim.x * 256;
    for (int i = blockIdx.x * 256 + threadIdx.x; i < N_EDGES; i += stride) {
        atomicAdd(&hE[e_col[i] >> SH_E], 1);
        atomicAdd(&hH[h_idx[i] >> SH_H], 1);
        atomicAdd(&hN[n_idx[i] >> SH_N], 1);
    }
    __syncthreads();
    for (int i = threadIdx.x; i < NB_E; i += 256) if (hE[i]) atomicAdd(&bcntE[i], hE[i]);
    for (int i = threadIdx.x; i < NB_H; i += 256) if (hH[i]) atomicAdd(&bcntH[i], hH[i]);
    for (int i = threadIdx.x; i < NB_N; i += 256) if (hN[i]) atomicAdd(&bcntN[i], hN[i]);
}

// ---------------- block-wide exclusive scan helper (n <= 1024) ----------------
__device__ void scan_block(const int* __restrict__ in, int* __restrict__ out, int n) {
    __shared__ int s[1024];
    int t = threadIdx.x;
    int chunk = (n + 1023) >> 10;
    int b = t * chunk;
    int e = min(b + chunk, n);
    int sum = 0;
    for (int i = b; i < e; ++i) sum += in[i];
    s[t] = sum;
    __syncthreads();
    for (int d = 1; d < 1024; d <<= 1) {
        int v = (t >= d) ? s[t - d] : 0;
        __syncthreads();
        s[t] += v;
        __syncthreads();
    }
    int run = (t > 0) ? s[t - 1] : 0;
    for (int i = b; i < e; ++i) { int v = in[i]; out[i] = run; run += v; }
}
__global__ void k_scan_buckets(const int* __restrict__ bcntE, int* __restrict__ boffE,
                               const int* __restrict__ bcntH, int* __restrict__ boffH,
                               const int* __restrict__ bcntN, int* __restrict__ boffN) {
    if (blockIdx.x == 0)      scan_block(bcntE, boffE, NB_E);
    else if (blockIdx.x == 1) scan_block(bcntH, boffH, NB_H);
    else                      scan_block(bcntN, boffN, NB_N);
}

// ---------------- pass B: chunked scatter with LDS staging (write-combining) ----------------
#define NBMAX 80
__device__ void chunk_scatter(const int* __restrict__ keys, const int* __restrict__ vals,
                              int n, int sh, int nb,
                              const int* __restrict__ boff, int* __restrict__ bcur,
                              int2* __restrict__ bk, int blk) {
    __shared__ int h[NBMAX], loc[NBMAX], base[NBMAX], hc[NBMAX];
    __shared__ int2 buf[TILE];
    int t0 = blk * TILE;
    int tend = min(t0 + TILE, n);
    int cnt = tend - t0;
    for (int b = threadIdx.x; b < nb; b += 256) { h[b] = 0; hc[b] = 0; }
    __syncthreads();
    for (int i = t0 + threadIdx.x; i < tend; i += 256)
        atomicAdd(&h[keys[i] >> sh], 1);
    __syncthreads();
    if (threadIdx.x == 0) {
        int run = 0;
        for (int b = 0; b < nb; ++b) { loc[b] = run; run += h[b]; }
    }
    __syncthreads();
    if (threadIdx.x < nb)
        base[threadIdx.x] = boff[threadIdx.x] + atomicAdd(&bcur[threadIdx.x], h[threadIdx.x]);
    __syncthreads();
    for (int i = t0 + threadIdx.x; i < tend; i += 256) {
        int k = keys[i];
        int b = k >> sh;
        int r = loc[b] + atomicAdd(&hc[b], 1);
        buf[r] = make_int2(k, vals[i]);
    }
    __syncthreads();
    for (int j = threadIdx.x; j < cnt; j += 256) {
        int2 kv = buf[j];
        int b = kv.x >> sh;
        bk[base[b] + (j - loc[b])] = kv;   // contiguous per-bucket runs, block-owned
    }
}
__global__ void k_chunk_all(const int* __restrict__ e_row, const int* __restrict__ e_col,
                            const int* __restrict__ n_idx, const int* __restrict__ h_idx,
                            const int* __restrict__ boffE, int* __restrict__ bcurE, int2* __restrict__ bkE,
                            const int* __restrict__ boffH, int* __restrict__ bcurH, int2* __restrict__ bkH,
                            const int* __restrict__ boffN, int* __restrict__ bcurN, int2* __restrict__ bkN) {
    int gb = blockIdx.x;
    if (gb < GB)            chunk_scatter(e_col, e_row, N_EDGES, SH_E, NB_E, boffE, bcurE, bkE, gb);
    else if (gb < 2 * GB)   chunk_scatter(h_idx, n_idx, NNZ_H,  SH_H, NB_H, boffH, bcurH, bkH, gb - GB);
    else                    chunk_scatter(n_idx, h_idx, NNZ_H,  SH_N, NB_N, boffN, bcurN, bkN, gb - 2 * GB);
}

// ---------------- pass C: per-bucket CSR finalize (LDS key-hist + scan + rank) ----------------
__global__ void k_fin_all(const int2* __restrict__ bkE, const int* __restrict__ boffE,
                          int* __restrict__ srtE, int* __restrict__ offE,
                          const int2* __restrict__ bkH, const int* __restrict__ boffH,
                          int* __restrict__ srtH, int* __restrict__ offH,
                          const int2* __restrict__ bkN, const int* __restrict__ boffN,
                          int* __restrict__ srtN, int* __restrict__ offN) {
    __shared__ int koff[1024];
    __shared__ int kcur[1024];
    __shared__ int tsum[256];
    int b = blockIdx.x;
    const int2* bk; const int* boff; int* srt; int* off;
    int nb, sh, nkeys, total;
    if (b < NB_E) {
        bk = bkE; boff = boffE; srt = srtE; off = offE;
        nb = NB_E; sh = SH_E; nkeys = N_NODES; total = N_EDGES;
    } else if (b < NB_E + NB_H) {
        b -= NB_E;
        bk = bkH; boff = boffH; srt = srtH; off = offH;
        nb = NB_H; sh = SH_H; nkeys = M_HE; total = NNZ_H;
    } else {
        b -= NB_E + NB_H;
        bk = bkN; boff = boffN; srt = srtN; off = offN;
        nb = NB_N; sh = SH_N; nkeys = N_NODES; total = NNZ_H;
    }
    int kpb = 1 << sh;
    int k0 = b << sh;
    int beg = boff[b];
    int end = (b + 1 < nb) ? boff[b + 1] : total;
    for (int k = threadIdx.x; k < kpb; k += 256) { koff[k] = 0; kcur[k] = 0; }
    __syncthreads();
    for (int i = beg + threadIdx.x; i < end; i += 256)
        atomicAdd(&koff[bk[i].x - k0], 1);
    __syncthreads();
    // block exclusive scan of koff[0..kpb)
    int CH = (kpb + 255) >> 8;
    int t = threadIdx.x;
    int c0 = t * CH;
    int lsum = 0;
    for (int c = 0; c < CH; ++c) { int k = c0 + c; if (k < kpb) lsum += koff[k]; }
    tsum[t] = lsum;
    __syncthreads();
    for (int d = 1; d < 256; d <<= 1) {
        int v = (t >= d) ? tsum[t - d] : 0;
        __syncthreads();
        tsum[t] += v;
        __syncthreads();
    }
    int run = (t > 0) ? tsum[t - 1] : 0;
    for (int c = 0; c < CH; ++c) {
        int k = c0 + c;
        if (k < kpb) { int v = koff[k]; koff[k] = run; run += v; }
    }
    __syncthreads();
    // CSR offsets
    for (int k = threadIdx.x; k < kpb; k += 256)
        if (k0 + k < nkeys) off[k0 + k] = beg + koff[k];
    if (b == nb - 1 && threadIdx.x == 0) off[nkeys] = total;
    // rank + scatter payload (block-owned contiguous window)
    for (int i = beg + threadIdx.x; i < end; i += 256) {
        int2 kv = bk[i];
        int lk = kv.x - k0;
        int pos = beg + koff[lk] + atomicAdd(&kcur[lk], 1);
        srt[pos] = kv.y;
    }
}

// ---------------- register-tiled GEMM: (rows x K) @ (K x 64) ----------------
// 64 rows x 64 cols per block (256 thr), 4x4 outputs/thread, K tiled by 64.
// SCALE: multiply row result by rsqrt(deg+1), deg from CSR offsets.
template<int K, bool SCALE>
__global__ void k_gemm(const float* __restrict__ xin, const float* __restrict__ w,
                       const int* __restrict__ offE, float* __restrict__ out) {
    __shared__ float wl[64 * 64];     // [kk][f]
    __shared__ float xs[64 * 68];     // [r][kk], pad 68 to break bank aliasing
    int tid = threadIdx.x;
    int wv = tid >> 6, lane = tid & 63;
    int cg = lane & 15;               // col group: cols 4cg..4cg+3
    int rg = lane >> 4;               // row group within wave
    int rl = wv * 16 + rg * 4;        // first of this thread's 4 local rows
    int r0 = blockIdx.x * 64;
    float acc[4][4] = {};
    for (int k0 = 0; k0 < K; k0 += 64) {
        // stage weight tile: 4096 contiguous floats at w + k0*64
        {
            const float4* wsrc = (const float4*)(w + k0 * 64);
            float4* wdst = (float4*)wl;
            for (int j = tid; j < 1024; j += 256) wdst[j] = wsrc[j];
        }
        // stage x tile: rows r0..r0+63, cols k0..k0+63 (row-coalesced float4)
        for (int p = tid; p < 1024; p += 256) {
            int r = p >> 4, c4 = p & 15;
            int row = min(r0 + r, N_NODES - 1);
            float4 v = *(const float4*)(xin + (size_t)row * K + k0 + 4 * c4);
            *(float4*)&xs[r * 68 + 4 * c4] = v;
        }
        __syncthreads();
#pragma unroll 4
        for (int kk = 0; kk < 64; ++kk) {
            float4 wf = *(const float4*)&wl[kk * 64 + cg * 4];
            float x0 = xs[(rl + 0) * 68 + kk];
            float x1 = xs[(rl + 1) * 68 + kk];
            float x2 = xs[(rl + 2) * 68 + kk];
            float x3 = xs[(rl + 3) * 68 + kk];
            acc[0][0] += x0 * wf.x; acc[0][1] += x0 * wf.y; acc[0][2] += x0 * wf.z; acc[0][3] += x0 * wf.w;
            acc[1][0] += x1 * wf.x; acc[1][1] += x1 * wf.y; acc[1][2] += x1 * wf.z; acc[1][3] += x1 * wf.w;
            acc[2][0] += x2 * wf.x; acc[2][1] += x2 * wf.y; acc[2][2] += x2 * wf.z; acc[2][3] += x2 * wf.w;
            acc[3][0] += x3 * wf.x; acc[3][1] += x3 * wf.y; acc[3][2] += x3 * wf.z; acc[3][3] += x3 * wf.w;
        }
        __syncthreads();
    }
#pragma unroll
    for (int i = 0; i < 4; ++i) {
        int row = r0 + rl + i;
        if (row < N_NODES) {
            float s = 1.0f;
            if (SCALE) {
                float deg = (float)(offE[row + 1] - offE[row]);
                s = rsqrtf(deg + 1.0f);
            }
            float4 o = make_float4(acc[i][0] * s, acc[i][1] * s, acc[i][2] * s, acc[i][3] * s);
            *(float4*)&out[(size_t)row * 64 + cg * 4] = o;
        }
    }
}

// ---------------- GCN gather on pre-scaled A': out = di*(sum + A'[i]) + b ----------------
template<bool ELU>
__global__ void k_gcn_gather(const int* __restrict__ off, const int* __restrict__ srcs,
                             const float* __restrict__ xw, const float* __restrict__ b,
                             float* __restrict__ out) {
    int wid = (blockIdx.x * blockDim.x + threadIdx.x) >> 6;
    int f = threadIdx.x & 63;
    if (wid >= N_NODES) return;
    int beg = off[wid], end = off[wid + 1];
    float a0 = 0, a1 = 0, a2 = 0, a3 = 0;
    int e = beg;
    for (; e + 4 <= end; e += 4) {
        int s0 = srcs[e], s1 = srcs[e + 1], s2 = srcs[e + 2], s3 = srcs[e + 3];
        a0 += xw[(size_t)s0 * 64 + f];
        a1 += xw[(size_t)s1 * 64 + f];
        a2 += xw[(size_t)s2 * 64 + f];
        a3 += xw[(size_t)s3 * 64 + f];
    }
    for (; e < end; ++e) a0 += xw[(size_t)srcs[e] * 64 + f];
    float acc = (a0 + a1) + (a2 + a3);
    float di = rsqrtf((float)(end - beg) + 1.0f);
    float v = di * (acc + xw[(size_t)wid * 64 + f]) + b[f];
    if (ELU) v = (v > 0.0f) ? v : expm1f(v);
    out[(size_t)wid * 64 + f] = v;
}

// ---------------- hyperedge gather: one BLOCK per hyperedge, 4-wave split + unroll ----------------
__global__ void k_he_gather(const int* __restrict__ off, const int* __restrict__ nodes,
                            const float* __restrict__ xw, float* __restrict__ C) {
    __shared__ float red[4][64];
    int he = blockIdx.x;
    int wv = threadIdx.x >> 6, f = threadIdx.x & 63;
    int beg = off[he], end = off[he + 1];
    int cnt = end - beg;
    int per = (cnt + 3) >> 2;
    int b0 = beg + wv * per;
    int e0 = min(b0 + per, end);
    float a0 = 0, a1 = 0, a2 = 0, a3 = 0;
    int e = b0;
    for (; e + 4 <= e0; e += 4) {
        int s0 = nodes[e], s1 = nodes[e + 1], s2 = nodes[e + 2], s3 = nodes[e + 3];
        a0 += xw[(size_t)s0 * 64 + f];
        a1 += xw[(size_t)s1 * 64 + f];
        a2 += xw[(size_t)s2 * 64 + f];
        a3 += xw[(size_t)s3 * 64 + f];
    }
    for (; e < e0; ++e) a0 += xw[(size_t)nodes[e] * 64 + f];
    red[wv][f] = (a0 + a1) + (a2 + a3);
    __syncthreads();
    if (wv == 0) {
        float tot = (red[0][f] + red[1][f]) + (red[2][f] + red[3][f]);
        float binv = (cnt > 0) ? 1.0f / (float)cnt : 0.0f;
        C[(size_t)he * 64 + f] = binv * tot;
    }
}

// ---------------- node gather from hyperedge feats: fused Dinv+bias+ELU ----------------
template<bool ELU>
__global__ void k_node_gather(const int* __restrict__ off, const int* __restrict__ hes,
                              const float* __restrict__ C, const float* __restrict__ b,
                              float* __restrict__ out) {
    int wid = (blockIdx.x * blockDim.x + threadIdx.x) >> 6;
    int f = threadIdx.x & 63;
    if (wid >= N_NODES) return;
    int beg = off[wid], end = off[wid + 1];
    float a0 = 0, a1 = 0, a2 = 0, a3 = 0;
    int e = beg;
    for (; e + 4 <= end; e += 4) {
        int s0 = hes[e], s1 = hes[e + 1], s2 = hes[e + 2], s3 = hes[e + 3];
        a0 += C[(size_t)s0 * 64 + f];
        a1 += C[(size_t)s1 * 64 + f];
        a2 += C[(size_t)s2 * 64 + f];
        a3 += C[(size_t)s3 * 64 + f];
    }
    for (; e < end; ++e) a0 += C[(size_t)hes[e] * 64 + f];
    float acc = (a0 + a1) + (a2 + a3);
    float dinv = (end > beg) ? 1.0f / (float)(end - beg) : 0.0f;
    float v = dinv * acc + b[f];
    if (ELU) v = (v > 0.0f) ? v : expm1f(v);
    out[(size_t)wid * 64 + f] = v;
}

// ---------------- fusion (float4) ----------------
__global__ void k_fuse(const float4* __restrict__ xs, const float4* __restrict__ xd,
                       const float* __restrict__ gate, float4* __restrict__ z) {
    int t = blockIdx.x * blockDim.x + threadIdx.x;
    if (t >= N_NODES * 16) return;
    float a = 1.0f / (1.0f + expf(-gate[0]));
    float4 s = xs[t], d = xd[t];
    float4 o;
    o.x = a * s.x + (1.0f - a) * d.x;
    o.y = a * s.y + (1.0f - a) * d.y;
    o.z = a * s.z + (1.0f - a) * d.z;
    o.w = a * s.w + (1.0f - a) * d.w;
    z[t] = o;
}

extern "C" void kernel_launch(void* const* d_in, const int* in_sizes, int n_in,
                              void* d_out, int out_size, void* d_ws, size_t ws_size,
                              hipStream_t stream) {
    const float* x      = (const float*)d_in[0];
    const int*   ei     = (const int*)d_in[1];
    const int*   hei    = (const int*)d_in[2];
    const float* gcn1_w = (const float*)d_in[3];
    const float* gcn1_b = (const float*)d_in[4];
    const float* gcn2_w = (const float*)d_in[5];
    const float* gcn2_b = (const float*)d_in[6];
    const float* hyp1_w = (const float*)d_in[7];
    const float* hyp1_b = (const float*)d_in[8];
    const float* hyp2_w = (const float*)d_in[9];
    const float* hyp2_b = (const float*)d_in[10];
    const float* gate   = (const float*)d_in[11];
    float* out = (float*)d_out;

    const int* e_row = ei;               // sources
    const int* e_col = ei + N_EDGES;     // targets
    const int* n_idx = hei;              // node ids
    const int* h_idx = hei + NNZ_H;      // hyperedge ids

    const size_t NV = (size_t)N_NODES * 64;
    float* z_out  = out;
    float* xs_out = out + NV;
    float* xd_out = out + 2 * NV;

    // ---- workspace layout ----
    float* A    = (float*)d_ws;          // N*64 floats
    float* AGG  = A + NV;                // N*64
    float* C    = AGG + NV;              // M*64
    int* srtE = (int*)(C + (size_t)M_HE * 64);  // E
    int* srtH = srtE + N_EDGES;          // NNZ
    int* srtN = srtH + NNZ_H;            // NNZ
    int* offE = srtN + NNZ_H;            // N+1
    int* offH = offE + (N_NODES + 1);    // M+1
    int* offN = offH + (M_HE + 1);       // N+1
    // contiguous zero block: bucket counts + cursors
    int* bcntE = offN + (N_NODES + 1);   // NB_E
    int* bcntH = bcntE + NB_E;           // NB_H
    int* bcntN = bcntH + NB_H;           // NB_N
    int* bcurE = bcntN + NB_N;           // NB_E
    int* bcurH = bcurE + NB_E;           // NB_H
    int* bcurN = bcurH + NB_H;           // NB_N
    // scan outputs (no zeroing needed)
    int* boffE = bcurN + NB_N;           // NB_E
    int* boffH = boffE + NB_E;           // NB_H
    int* boffN = boffH + NB_H;           // NB_N
    const size_t zero_ints = 2 * (size_t)(NB_E + NB_H + NB_N);
    // bucket staging aliases A/AGG (free during CSR build)
    int2* bkE = (int2*)A;                          // 6.4 MB
    int2* bkH = (int2*)(A + 2 * (size_t)N_EDGES);  // 6.4 MB
    int2* bkN = (int2*)AGG;                        // 6.4 MB

    const int BLK = 256;
    const int gWN  = N_NODES / 4;                      // 12500 wave-per-node blocks
    const int gG   = (N_NODES + 63) / 64;              // 782 GEMM blocks
    const int gF4  = (N_NODES * 16 + BLK - 1) / BLK;

    // ---- CSR build: two-level bucketed counting sort with chunked (write-combined) scatter ----
    hipMemsetAsync(bcntE, 0, zero_ints * sizeof(int), stream);
    k_hist_all<<<256, BLK, 0, stream>>>(e_col, h_idx, n_idx, bcntE, bcntH, bcntN);
    k_scan_buckets<<<3, 1024, 0, stream>>>(bcntE, boffE, bcntH, boffH, bcntN, boffN);
    k_chunk_all<<<3 * GB, BLK, 0, stream>>>(e_row, e_col, n_idx, h_idx,
                                            boffE, bcurE, bkE,
                                            boffH, bcurH, bkH,
                                            boffN, bcurN, bkN);
    k_fin_all<<<NB_E + NB_H + NB_N, BLK, 0, stream>>>(bkE, boffE, srtE, offE,
                                                      bkH, boffH, srtH, offH,
                                                      bkN, boffN, srtN, offN);

    // ---- GCN layer 1: A = dis.*(x@w1) ; AGG = ELU(di*(gather+self) + b1) ----
    k_gemm<F_IN, true><<<gG, BLK, 0, stream>>>(x, gcn1_w, offE, A);
    k_gcn_gather<true><<<gWN, BLK, 0, stream>>>(offE, srtE, A, gcn1_b, AGG);

    // ---- GCN layer 2 ----
    k_gemm<F_HID, true><<<gG, BLK, 0, stream>>>(AGG, gcn2_w, offE, A);
    k_gcn_gather<false><<<gWN, BLK, 0, stream>>>(offE, srtE, A, gcn2_b, xs_out);

    // ---- Hyper layer 1 ----
    k_gemm<F_IN, false><<<gG, BLK, 0, stream>>>(x, hyp1_w, nullptr, A);
    k_he_gather<<<M_HE, BLK, 0, stream>>>(offH, srtH, A, C);
    k_node_gather<true><<<gWN, BLK, 0, stream>>>(offN, srtN, C, hyp1_b, AGG);

    // ---- Hyper layer 2 ----
    k_gemm<F_HID, false><<<gG, BLK, 0, stream>>>(AGG, hyp2_w, nullptr, A);
    k_he_gather<<<M_HE, BLK, 0, stream>>>(offH, srtH, A, C);
    k_node_gather<false><<<gWN, BLK, 0, stream>>>(offN, srtN, C, hyp2_b, xd_out);

    // ---- fusion ----
    k_fuse<<<gF4, BLK, 0, stream>>>((const float4*)xs_out, (const float4*)xd_out, gate, (float4*)z_out);

    (void)in_sizes; (void)n_in; (void)out_size; (void)ws_size;
}

// Round 9
// 342.125 us; speedup vs baseline: 2.2596x; 1.0695x over previous
//
#include <hip/hip_runtime.h>
#include <hip/hip_bf16.h>

#define N_NODES 50000
#define N_EDGES 800000
#define NNZ_H   800000
#define M_HE    10000
#define F_IN    128
#define F_HID   64

// coarse-bucket geometry for the two-level counting sort
#define SH_E 7
#define NB_E ((N_NODES + 127) >> 7)     // 391
#define SH_H 5
#define NB_H ((M_HE + 31) >> 5)         // 313
#define SH_N 7
#define NB_N ((N_NODES + 127) >> 7)     // 391
#define TILE 4096
#define GB   ((N_EDGES + TILE - 1) / TILE)   // 196 (E == NNZ)
#define NBMAX 400
#define KPBMAX 128

// ---------------- pass A: fused bucket histograms (LDS pre-aggregated) ----------------
__global__ void k_hist_all(const int* __restrict__ e_col, const int* __restrict__ h_idx,
                           const int* __restrict__ n_idx,
                           int* __restrict__ bcntE, int* __restrict__ bcntH, int* __restrict__ bcntN) {
    __shared__ int hE[NB_E], hH[NB_H], hN[NB_N];
    for (int i = threadIdx.x; i < NB_E; i += 256) hE[i] = 0;
    for (int i = threadIdx.x; i < NB_H; i += 256) hH[i] = 0;
    for (int i = threadIdx.x; i < NB_N; i += 256) hN[i] = 0;
    __syncthreads();
    int stride = gridDim.x * 256;
    for (int i = blockIdx.x * 256 + threadIdx.x; i < N_EDGES; i += stride) {
        atomicAdd(&hE[e_col[i] >> SH_E], 1);
        atomicAdd(&hH[h_idx[i] >> SH_H], 1);
        atomicAdd(&hN[n_idx[i] >> SH_N], 1);
    }
    __syncthreads();
    for (int i = threadIdx.x; i < NB_E; i += 256) if (hE[i]) atomicAdd(&bcntE[i], hE[i]);
    for (int i = threadIdx.x; i < NB_H; i += 256) if (hH[i]) atomicAdd(&bcntH[i], hH[i]);
    for (int i = threadIdx.x; i < NB_N; i += 256) if (hN[i]) atomicAdd(&bcntN[i], hN[i]);
}

// ---------------- block-wide exclusive scan helper (n <= 1024) ----------------
__device__ void scan_block(const int* __restrict__ in, int* __restrict__ out, int n) {
    __shared__ int s[1024];
    int t = threadIdx.x;
    int chunk = (n + 1023) >> 10;
    int b = t * chunk;
    int e = min(b + chunk, n);
    int sum = 0;
    for (int i = b; i < e; ++i) sum += in[i];
    s[t] = sum;
    __syncthreads();
    for (int d = 1; d < 1024; d <<= 1) {
        int v = (t >= d) ? s[t - d] : 0;
        __syncthreads();
        s[t] += v;
        __syncthreads();
    }
    int run = (t > 0) ? s[t - 1] : 0;
    for (int i = b; i < e; ++i) { int v = in[i]; out[i] = run; run += v; }
}
__global__ void k_scan_buckets(const int* __restrict__ bcntE, int* __restrict__ boffE,
                               const int* __restrict__ bcntH, int* __restrict__ boffH,
                               const int* __restrict__ bcntN, int* __restrict__ boffN) {
    if (blockIdx.x == 0)      scan_block(bcntE, boffE, NB_E);
    else if (blockIdx.x == 1) scan_block(bcntH, boffH, NB_H);
    else                      scan_block(bcntN, boffN, NB_N);
}

// ---------------- pass B: chunked scatter with LDS staging (write-combining) ----------------
__device__ void chunk_scatter(const int* __restrict__ keys, const int* __restrict__ vals,
                              int n, int sh, int nb,
                              const int* __restrict__ boff, int* __restrict__ bcur,
                              int2* __restrict__ bk, int blk) {
    __shared__ int h[NBMAX], loc[NBMAX], base[NBMAX], hc[NBMAX];
    __shared__ int2 buf[TILE];
    int t0 = blk * TILE;
    int tend = min(t0 + TILE, n);
    int cnt = tend - t0;
    for (int b = threadIdx.x; b < nb; b += 256) { h[b] = 0; hc[b] = 0; }
    __syncthreads();
    for (int i = t0 + threadIdx.x; i < tend; i += 256)
        atomicAdd(&h[keys[i] >> sh], 1);
    __syncthreads();
    if (threadIdx.x == 0) {
        int run = 0;
        for (int b = 0; b < nb; ++b) { loc[b] = run; run += h[b]; }
    }
    __syncthreads();
    for (int b = threadIdx.x; b < nb; b += 256)
        base[b] = boff[b] + atomicAdd(&bcur[b], h[b]);
    __syncthreads();
    for (int i = t0 + threadIdx.x; i < tend; i += 256) {
        int k = keys[i];
        int b = k >> sh;
        int r = loc[b] + atomicAdd(&hc[b], 1);
        buf[r] = make_int2(k, vals[i]);
    }
    __syncthreads();
    for (int j = threadIdx.x; j < cnt; j += 256) {
        int2 kv = buf[j];
        int b = kv.x >> sh;
        bk[base[b] + (j - loc[b])] = kv;   // contiguous per-bucket runs, block-owned
    }
}
__global__ void k_chunk_all(const int* __restrict__ e_row, const int* __restrict__ e_col,
                            const int* __restrict__ n_idx, const int* __restrict__ h_idx,
                            const int* __restrict__ boffE, int* __restrict__ bcurE, int2* __restrict__ bkE,
                            const int* __restrict__ boffH, int* __restrict__ bcurH, int2* __restrict__ bkH,
                            const int* __restrict__ boffN, int* __restrict__ bcurN, int2* __restrict__ bkN) {
    int gb = blockIdx.x;
    if (gb < GB)            chunk_scatter(e_col, e_row, N_EDGES, SH_E, NB_E, boffE, bcurE, bkE, gb);
    else if (gb < 2 * GB)   chunk_scatter(h_idx, n_idx, NNZ_H,  SH_H, NB_H, boffH, bcurH, bkH, gb - GB);
    else                    chunk_scatter(n_idx, h_idx, NNZ_H,  SH_N, NB_N, boffN, bcurN, bkN, gb - 2 * GB);
}

// ---------------- pass C: per-bucket CSR finalize (LDS key-hist + scan + rank) ----------------
__global__ void k_fin_all(const int2* __restrict__ bkE, const int* __restrict__ boffE,
                          int* __restrict__ srtE, int* __restrict__ offE,
                          const int2* __restrict__ bkH, const int* __restrict__ boffH,
                          int* __restrict__ srtH, int* __restrict__ offH,
                          const int2* __restrict__ bkN, const int* __restrict__ boffN,
                          int* __restrict__ srtN, int* __restrict__ offN) {
    __shared__ int koff[KPBMAX];
    __shared__ int kcur[KPBMAX];
    __shared__ int tsum[256];
    int b = blockIdx.x;
    const int2* bk; const int* boff; int* srt; int* off;
    int nb, sh, nkeys, total;
    if (b < NB_E) {
        bk = bkE; boff = boffE; srt = srtE; off = offE;
        nb = NB_E; sh = SH_E; nkeys = N_NODES; total = N_EDGES;
    } else if (b < NB_E + NB_H) {
        b -= NB_E;
        bk = bkH; boff = boffH; srt = srtH; off = offH;
        nb = NB_H; sh = SH_H; nkeys = M_HE; total = NNZ_H;
    } else {
        b -= NB_E + NB_H;
        bk = bkN; boff = boffN; srt = srtN; off = offN;
        nb = NB_N; sh = SH_N; nkeys = N_NODES; total = NNZ_H;
    }
    int kpb = 1 << sh;
    int k0 = b << sh;
    int beg = boff[b];
    int end = (b + 1 < nb) ? boff[b + 1] : total;
    int t = threadIdx.x;
    if (t < kpb) { koff[t] = 0; kcur[t] = 0; }
    __syncthreads();
    for (int i = beg + t; i < end; i += 256)
        atomicAdd(&koff[bk[i].x - k0], 1);
    __syncthreads();
    // block exclusive scan of koff[0..kpb)
    int v = (t < kpb) ? koff[t] : 0;
    tsum[t] = v;
    __syncthreads();
    for (int d = 1; d < 256; d <<= 1) {
        int u = (t >= d) ? tsum[t - d] : 0;
        __syncthreads();
        tsum[t] += u;
        __syncthreads();
    }
    if (t < kpb) koff[t] = tsum[t] - v;   // exclusive
    __syncthreads();
    // CSR offsets
    if (t < kpb && (k0 + t) < nkeys) off[k0 + t] = beg + koff[t];
    if (b == nb - 1 && t == 0) off[nkeys] = total;
    // rank + scatter payload (block-owned contiguous window)
    for (int i = beg + t; i < end; i += 256) {
        int2 kv = bk[i];
        int lk = kv.x - k0;
        int pos = beg + koff[lk] + atomicAdd(&kcur[lk], 1);
        srt[pos] = kv.y;
    }
}

// ---------------- register-tiled GEMM: (rows x K) @ (K x 64) ----------------
template<int K, bool SCALE>
__global__ void k_gemm(const float* __restrict__ xin, const float* __restrict__ w,
                       const int* __restrict__ offE, float* __restrict__ out) {
    __shared__ float wl[64 * 64];     // [kk][f]
    __shared__ float xs[64 * 68];     // [r][kk], pad 68 to break bank aliasing
    int tid = threadIdx.x;
    int wv = tid >> 6, lane = tid & 63;
    int cg = lane & 15;               // col group: cols 4cg..4cg+3
    int rg = lane >> 4;               // row group within wave
    int rl = wv * 16 + rg * 4;        // first of this thread's 4 local rows
    int r0 = blockIdx.x * 64;
    float acc[4][4] = {};
    for (int k0 = 0; k0 < K; k0 += 64) {
        {
            const float4* wsrc = (const float4*)(w + k0 * 64);
            float4* wdst = (float4*)wl;
            for (int j = tid; j < 1024; j += 256) wdst[j] = wsrc[j];
        }
        for (int p = tid; p < 1024; p += 256) {
            int r = p >> 4, c4 = p & 15;
            int row = min(r0 + r, N_NODES - 1);
            float4 v = *(const float4*)(xin + (size_t)row * K + k0 + 4 * c4);
            *(float4*)&xs[r * 68 + 4 * c4] = v;
        }
        __syncthreads();
#pragma unroll 4
        for (int kk = 0; kk < 64; ++kk) {
            float4 wf = *(const float4*)&wl[kk * 64 + cg * 4];
            float x0 = xs[(rl + 0) * 68 + kk];
            float x1 = xs[(rl + 1) * 68 + kk];
            float x2 = xs[(rl + 2) * 68 + kk];
            float x3 = xs[(rl + 3) * 68 + kk];
            acc[0][0] += x0 * wf.x; acc[0][1] += x0 * wf.y; acc[0][2] += x0 * wf.z; acc[0][3] += x0 * wf.w;
            acc[1][0] += x1 * wf.x; acc[1][1] += x1 * wf.y; acc[1][2] += x1 * wf.z; acc[1][3] += x1 * wf.w;
            acc[2][0] += x2 * wf.x; acc[2][1] += x2 * wf.y; acc[2][2] += x2 * wf.z; acc[2][3] += x2 * wf.w;
            acc[3][0] += x3 * wf.x; acc[3][1] += x3 * wf.y; acc[3][2] += x3 * wf.z; acc[3][3] += x3 * wf.w;
        }
        __syncthreads();
    }
#pragma unroll
    for (int i = 0; i < 4; ++i) {
        int row = r0 + rl + i;
        if (row < N_NODES) {
            float s = 1.0f;
            if (SCALE) {
                float deg = (float)(offE[row + 1] - offE[row]);
                s = rsqrtf(deg + 1.0f);
            }
            float4 o = make_float4(acc[i][0] * s, acc[i][1] * s, acc[i][2] * s, acc[i][3] * s);
            *(float4*)&out[(size_t)row * 64 + cg * 4] = o;
        }
    }
}

// ---------------- GCN gather on pre-scaled A': out = di*(sum + A'[i]) + b ----------------
template<bool ELU>
__global__ void k_gcn_gather(const int* __restrict__ off, const int* __restrict__ srcs,
                             const float* __restrict__ xw, const float* __restrict__ b,
                             float* __restrict__ out) {
    int wid = (blockIdx.x * blockDim.x + threadIdx.x) >> 6;
    int f = threadIdx.x & 63;
    if (wid >= N_NODES) return;
    int beg = off[wid], end = off[wid + 1];
    float a0 = 0, a1 = 0, a2 = 0, a3 = 0;
    int e = beg;
    for (; e + 4 <= end; e += 4) {
        int s0 = srcs[e], s1 = srcs[e + 1], s2 = srcs[e + 2], s3 = srcs[e + 3];
        a0 += xw[(size_t)s0 * 64 + f];
        a1 += xw[(size_t)s1 * 64 + f];
        a2 += xw[(size_t)s2 * 64 + f];
        a3 += xw[(size_t)s3 * 64 + f];
    }
    for (; e < end; ++e) a0 += xw[(size_t)srcs[e] * 64 + f];
    float acc = (a0 + a1) + (a2 + a3);
    float di = rsqrtf((float)(end - beg) + 1.0f);
    float v = di * (acc + xw[(size_t)wid * 64 + f]) + b[f];
    if (ELU) v = (v > 0.0f) ? v : expm1f(v);
    out[(size_t)wid * 64 + f] = v;
}

// ---------------- hyperedge gather: one BLOCK per hyperedge, 4-wave split + unroll ----------------
__global__ void k_he_gather(const int* __restrict__ off, const int* __restrict__ nodes,
                            const float* __restrict__ xw, float* __restrict__ C) {
    __shared__ float red[4][64];
    int he = blockIdx.x;
    int wv = threadIdx.x >> 6, f = threadIdx.x & 63;
    int beg = off[he], end = off[he + 1];
    int cnt = end - beg;
    int per = (cnt + 3) >> 2;
    int b0 = beg + wv * per;
    int e0 = min(b0 + per, end);
    float a0 = 0, a1 = 0, a2 = 0, a3 = 0;
    int e = b0;
    for (; e + 4 <= e0; e += 4) {
        int s0 = nodes[e], s1 = nodes[e + 1], s2 = nodes[e + 2], s3 = nodes[e + 3];
        a0 += xw[(size_t)s0 * 64 + f];
        a1 += xw[(size_t)s1 * 64 + f];
        a2 += xw[(size_t)s2 * 64 + f];
        a3 += xw[(size_t)s3 * 64 + f];
    }
    for (; e < e0; ++e) a0 += xw[(size_t)nodes[e] * 64 + f];
    red[wv][f] = (a0 + a1) + (a2 + a3);
    __syncthreads();
    if (wv == 0) {
        float tot = (red[0][f] + red[1][f]) + (red[2][f] + red[3][f]);
        float binv = (cnt > 0) ? 1.0f / (float)cnt : 0.0f;
        C[(size_t)he * 64 + f] = binv * tot;
    }
}

// ---------------- node gather from hyperedge feats: fused Dinv+bias+ELU (+final fusion) ----------------
template<bool ELU, bool FUSE>
__global__ void k_node_gather(const int* __restrict__ off, const int* __restrict__ hes,
                              const float* __restrict__ C, const float* __restrict__ b,
                              float* __restrict__ out,
                              const float* __restrict__ xs, const float* __restrict__ gate,
                              float* __restrict__ z) {
    int wid = (blockIdx.x * blockDim.x + threadIdx.x) >> 6;
    int f = threadIdx.x & 63;
    if (wid >= N_NODES) return;
    int beg = off[wid], end = off[wid + 1];
    float a0 = 0, a1 = 0, a2 = 0, a3 = 0;
    int e = beg;
    for (; e + 4 <= end; e += 4) {
        int s0 = hes[e], s1 = hes[e + 1], s2 = hes[e + 2], s3 = hes[e + 3];
        a0 += C[(size_t)s0 * 64 + f];
        a1 += C[(size_t)s1 * 64 + f];
        a2 += C[(size_t)s2 * 64 + f];
        a3 += C[(size_t)s3 * 64 + f];
    }
    for (; e < end; ++e) a0 += C[(size_t)hes[e] * 64 + f];
    float acc = (a0 + a1) + (a2 + a3);
    float dinv = (end > beg) ? 1.0f / (float)(end - beg) : 0.0f;
    float v = dinv * acc + b[f];
    if (ELU) v = (v > 0.0f) ? v : expm1f(v);
    size_t idx = (size_t)wid * 64 + f;
    out[idx] = v;
    if (FUSE) {
        float a = 1.0f / (1.0f + expf(-gate[0]));
        z[idx] = a * xs[idx] + (1.0f - a) * v;
    }
}

extern "C" void kernel_launch(void* const* d_in, const int* in_sizes, int n_in,
                              void* d_out, int out_size, void* d_ws, size_t ws_size,
                              hipStream_t stream) {
    const float* x      = (const float*)d_in[0];
    const int*   ei     = (const int*)d_in[1];
    const int*   hei    = (const int*)d_in[2];
    const float* gcn1_w = (const float*)d_in[3];
    const float* gcn1_b = (const float*)d_in[4];
    const float* gcn2_w = (const float*)d_in[5];
    const float* gcn2_b = (const float*)d_in[6];
    const float* hyp1_w = (const float*)d_in[7];
    const float* hyp1_b = (const float*)d_in[8];
    const float* hyp2_w = (const float*)d_in[9];
    const float* hyp2_b = (const float*)d_in[10];
    const float* gate   = (const float*)d_in[11];
    float* out = (float*)d_out;

    const int* e_row = ei;               // sources
    const int* e_col = ei + N_EDGES;     // targets
    const int* n_idx = hei;              // node ids
    const int* h_idx = hei + NNZ_H;      // hyperedge ids

    const size_t NV = (size_t)N_NODES * 64;
    float* z_out  = out;
    float* xs_out = out + NV;
    float* xd_out = out + 2 * NV;

    // ---- workspace layout ----
    float* A    = (float*)d_ws;          // N*64 floats
    float* AGG  = A + NV;                // N*64
    float* C    = AGG + NV;              // M*64
    int* srtE = (int*)(C + (size_t)M_HE * 64);  // E
    int* srtH = srtE + N_EDGES;          // NNZ
    int* srtN = srtH + NNZ_H;            // NNZ
    int* offE = srtN + NNZ_H;            // N+1
    int* offH = offE + (N_NODES + 1);    // M+1
    int* offN = offH + (M_HE + 1);       // N+1
    // contiguous zero block: bucket counts + cursors
    int* bcntE = offN + (N_NODES + 1);   // NB_E
    int* bcntH = bcntE + NB_E;           // NB_H
    int* bcntN = bcntH + NB_H;           // NB_N
    int* bcurE = bcntN + NB_N;           // NB_E
    int* bcurH = bcurE + NB_E;           // NB_H
    int* bcurN = bcurH + NB_H;           // NB_N
    // scan outputs (no zeroing needed)
    int* boffE = bcurN + NB_N;           // NB_E
    int* boffH = boffE + NB_E;           // NB_H
    int* boffN = boffH + NB_H;           // NB_N
    const size_t zero_ints = 2 * (size_t)(NB_E + NB_H + NB_N);
    // bucket staging aliases A/AGG (free during CSR build)
    int2* bkE = (int2*)A;                          // 6.4 MB
    int2* bkH = (int2*)(A + 2 * (size_t)N_EDGES);  // 6.4 MB
    int2* bkN = (int2*)AGG;                        // 6.4 MB

    const int BLK = 256;
    const int gWN  = N_NODES / 4;                      // 12500 wave-per-node blocks
    const int gG   = (N_NODES + 63) / 64;              // 782 GEMM blocks

    // ---- CSR build: two-level bucketed counting sort with chunked (write-combined) scatter ----
    hipMemsetAsync(bcntE, 0, zero_ints * sizeof(int), stream);
    k_hist_all<<<256, BLK, 0, stream>>>(e_col, h_idx, n_idx, bcntE, bcntH, bcntN);
    k_scan_buckets<<<3, 1024, 0, stream>>>(bcntE, boffE, bcntH, boffH, bcntN, boffN);
    k_chunk_all<<<3 * GB, BLK, 0, stream>>>(e_row, e_col, n_idx, h_idx,
                                            boffE, bcurE, bkE,
                                            boffH, bcurH, bkH,
                                            boffN, bcurN, bkN);
    k_fin_all<<<NB_E + NB_H + NB_N, BLK, 0, stream>>>(bkE, boffE, srtE, offE,
                                                      bkH, boffH, srtH, offH,
                                                      bkN, boffN, srtN, offN);

    // ---- GCN layer 1: A = dis.*(x@w1) ; AGG = ELU(di*(gather+self) + b1) ----
    k_gemm<F_IN, true><<<gG, BLK, 0, stream>>>(x, gcn1_w, offE, A);
    k_gcn_gather<true><<<gWN, BLK, 0, stream>>>(offE, srtE, A, gcn1_b, AGG);

    // ---- GCN layer 2 ----
    k_gemm<F_HID, true><<<gG, BLK, 0, stream>>>(AGG, gcn2_w, offE, A);
    k_gcn_gather<false><<<gWN, BLK, 0, stream>>>(offE, srtE, A, gcn2_b, xs_out);

    // ---- Hyper layer 1 ----
    k_gemm<F_IN, false><<<gG, BLK, 0, stream>>>(x, hyp1_w, nullptr, A);
    k_he_gather<<<M_HE, BLK, 0, stream>>>(offH, srtH, A, C);
    k_node_gather<true, false><<<gWN, BLK, 0, stream>>>(offN, srtN, C, hyp1_b, AGG,
                                                        nullptr, nullptr, nullptr);

    // ---- Hyper layer 2 (+ fused gating) ----
    k_gemm<F_HID, false><<<gG, BLK, 0, stream>>>(AGG, hyp2_w, nullptr, A);
    k_he_gather<<<M_HE, BLK, 0, stream>>>(offH, srtH, A, C);
    k_node_gather<false, true><<<gWN, BLK, 0, stream>>>(offN, srtN, C, hyp2_b, xd_out,
                                                        xs_out, gate, z_out);

    (void)in_sizes; (void)n_in; (void)out_size; (void)ws_size;
}